// Round 5
// baseline (368.173 us; speedup 1.0000x reference)
//
#include <hip/hip_runtime.h>
#include <hip/hip_cooperative_groups.h>

// Cost volume: B=4, C=32, H=256, W=256, D=9, G=8, cpg=4
// out[b,g,d,h,w] = mean_{c in group g} var(warp_l, warp_r, feat_ref)
//
// R6: chip-wide read/write phase separation (cooperative launch).
// Five structurally different kernels (R1-R5: scalar/low-VALU/LDS-staged/
// row-pipelined/float4) all pinned at 55-67us with byte-identical
// FETCH=53.3MB / WRITE=73.7MB and no saturated CU-side resource => the
// limiter is a chip-level service rate (~2.3 TB/s HBM vs 6.3 TB/s copy
// ceiling). The untested pattern delta vs the copy benchmark: fine-grained
// chip-wide read/write interleaving. This version:
//   Phase 1 (pure reads): 1024 blocks x 256 thr (4/CU, all resident),
//     each block runs R3's verified LDS core over 8 rows, stashing all
//     9 d-outputs per row in registers (float stash[8][9], fully
//     unrolled -> static indices, no scratch).
//   grid.sync()  (cooperative groups)
//   Phase 2 (pure writes): d-major nontemporal stores, 8KB contiguous
//     per output plane per block.
// Fallback: if hipLaunchCooperativeKernel is rejected, launch a plain
// variant (compute+store per row, no grid sync) == R3 behavior.

#define B_ 4
#define C_ 32
#define H_ 256
#define W_ 256
#define D_ 9
#define G_ 8
#define CPG 4
#define HW_ (H_ * W_)
#define SW_ 260       // staged row: x in [-2, W+1]
#define ROWS 8        // rows per block

namespace cg = cooperative_groups;

typedef float v2f __attribute__((ext_vector_type(2)));

static __device__ __forceinline__ v2f sp(float x) { v2f r; r.x = x; r.y = x; return r; }

template <bool COOP>
__global__ __launch_bounds__(256, 4) void cost_volume_kernel(
    const float* __restrict__ fref,
    const float* __restrict__ fls,
    const float* __restrict__ frs,
    const float* __restrict__ disp0,
    float* __restrict__ out)
{
    const float kRes[D_] = {-0.4f, -0.3f, -0.2f, -0.1f, 0.0f,
                             0.1f,  0.2f,  0.3f,  0.4f};

    __shared__ float sL[CPG][SW_];
    __shared__ float sR[CPG][SW_];

    const int bid = blockIdx.x;
    const int g  = bid & (G_ - 1);
    const int t  = bid >> 3;            // 0..127
    const int b  = t >> 5;              // 0..3
    const int h0 = (t & 31) * ROWS;     // 8-row band
    const int w  = threadIdx.x;
    const float wf = (float)w;

    float stash[ROWS][D_];              // static-indexed (full unroll)

    const unsigned rowbase0 = (unsigned)(((b * C_ + g * CPG) * HW_) + h0 * W_);
    const unsigned obase0 = (unsigned)(((b * G_ + g) * D_) * HW_ + h0 * W_ + w);

    #pragma unroll
    for (int r = 0; r < ROWS; ++r) {
        const int h = h0 + r;
        const float dbase = disp0[(unsigned)((b * H_ + h) * W_ + w)];

        const float* __restrict__ lsrow = fls  + rowbase0 + (unsigned)(r * W_);
        const float* __restrict__ rsrow = frs  + rowbase0 + (unsigned)(r * W_);
        const float* __restrict__ rfrow = fref + rowbase0 + (unsigned)(r * W_);

        // ---- stage L/R rows with halo into LDS (coalesced, disp-indep) ----
        {
            const int x = w - 2;                       // x = -2 .. 253
            const bool v = (unsigned)x < (unsigned)W_;
            #pragma unroll
            for (int cc = 0; cc < CPG; ++cc) {
                sL[cc][w] = v ? lsrow[cc * HW_ + x] : 0.0f;
                sR[cc][w] = v ? rsrow[cc * HW_ + x] : 0.0f;
            }
            if (w < SW_ - W_) {                        // 4 threads: x = 254..257
                const int x2 = W_ - 2 + w;
                const bool v2 = x2 < W_;
                #pragma unroll
                for (int cc = 0; cc < CPG; ++cc) {
                    sL[cc][W_ + w] = v2 ? lsrow[cc * HW_ + x2] : 0.0f;
                    sR[cc][W_ + w] = v2 ? rsrow[cc * HW_ + x2] : 0.0f;
                }
            }
        }

        v2f fr01, fr23;
        fr01.x = rfrow[(unsigned)w];
        fr01.y = rfrow[HW_ + (unsigned)w];
        fr23.x = rfrow[2u * HW_ + (unsigned)w];
        fr23.y = rfrow[3u * HW_ + (unsigned)w];
        const float frq = fr01.x * fr01.x + fr01.y * fr01.y
                        + fr23.x * fr23.x + fr23.y * fr23.y;

        __syncthreads();

        // ---- disp-dependent setup (R3 math, verified) ----
        const float s0 = wf + dbase;
        const int i0l = (int)floorf(s0 - 0.4f);
        int relL = i0l - w;
        relL = relL < -1 ? -1 : (relL > 0 ? 0 : relL);
        const float a1l = (s0 - (float)(w + relL)) - 1.0f;

        const float s1 = wf - dbase;
        const int i0r = (int)floorf(s1 - 0.4f);
        int relR = i0r - w;
        relR = relR < -2 ? -2 : (relR > -1 ? -1 : relR);
        const float a1r = (s1 - (float)(w + relR)) - 1.0f;

        const int baseL = w + relL + 2;
        const int baseR = w + relR + 2;

        v2f tl01[3], tl23[3], tr01[3], tr23[3];
        #pragma unroll
        for (int k = 0; k < 3; ++k) {
            tl01[k].x = sL[0][baseL + k];
            tl01[k].y = sL[1][baseL + k];
            tl23[k].x = sL[2][baseL + k];
            tl23[k].y = sL[3][baseL + k];
            tr01[k].x = sR[0][baseR + k];
            tr01[k].y = sR[1][baseR + k];
            tr23[k].x = sR[2][baseR + k];
            tr23[k].y = sR[3][baseR + k];
        }

        #pragma unroll
        for (int d = 0; d < D_; ++d) {
            const float tlw = a1l + kRes[d];
            const float W0l = fmaxf(-tlw, 0.0f);
            const float W1l = 1.0f - fabsf(tlw);
            const float W2l = fmaxf(tlw, 0.0f);
            const float trw = a1r - kRes[d];
            const float W0r = fmaxf(-trw, 0.0f);
            const float W1r = 1.0f - fabsf(trw);
            const float W2r = fmaxf(trw, 0.0f);

            v2f wl01 = tl01[0] * sp(W0l) + tl01[1] * sp(W1l) + tl01[2] * sp(W2l);
            v2f wl23 = tl23[0] * sp(W0l) + tl23[1] * sp(W1l) + tl23[2] * sp(W2l);
            v2f wr01 = tr01[0] * sp(W0r) + tr01[1] * sp(W1r) + tr01[2] * sp(W2r);
            v2f wr23 = tr23[0] * sp(W0r) + tr23[1] * sp(W1r) + tr23[2] * sp(W2r);

            v2f q   = wl01 * wl01 + wr01 * wr01 + wl23 * wl23 + wr23 * wr23;
            v2f s01 = wl01 + wr01 + fr01;
            v2f s23 = wl23 + wr23 + fr23;
            v2f s2  = s01 * s01 + s23 * s23;

            const float Q  = q.x + q.y + frq;
            const float S2 = s2.x + s2.y;
            const float val = (Q - S2 * (1.0f / 3.0f)) * (1.0f / 12.0f);

            if constexpr (COOP) {
                stash[r][d] = val;
            } else {
                __builtin_nontemporal_store(
                    val, &out[obase0 + (unsigned)(d * HW_ + r * W_)]);
            }
        }

        if (r + 1 < ROWS) __syncthreads();   // LDS reuse next row
    }

    if constexpr (COOP) {
        // ---- chip-wide barrier: all reads done before any write ----
        cg::this_grid().sync();

        // ---- pure write phase: d-major, 8KB contiguous per plane ----
        #pragma unroll
        for (int d = 0; d < D_; ++d) {
            #pragma unroll
            for (int r = 0; r < ROWS; ++r) {
                __builtin_nontemporal_store(
                    stash[r][d] , &out[obase0 + (unsigned)(d * HW_ + r * W_)]);
            }
        }
    }
}

extern "C" void kernel_launch(void* const* d_in, const int* in_sizes, int n_in,
                              void* d_out, int out_size, void* d_ws, size_t ws_size,
                              hipStream_t stream) {
    const float* fref  = (const float*)d_in[0];
    const float* fls   = (const float*)d_in[1];
    const float* frs   = (const float*)d_in[2];
    const float* disp0 = (const float*)d_in[3];
    float* out = (float*)d_out;

    dim3 grid(B_ * G_ * (H_ / ROWS));    // 1024 blocks = 4/CU, all resident
    dim3 block(256);

    void* args[] = {(void*)&fref, (void*)&fls, (void*)&frs,
                    (void*)&disp0, (void*)&out};
    hipError_t e = hipLaunchCooperativeKernel(
        (const void*)&cost_volume_kernel<true>, grid, block, args, 0, stream);
    if (e != hipSuccess) {
        // graph-capture / platform fallback: plain launch, per-row stores
        cost_volume_kernel<false><<<grid, block, 0, stream>>>(
            fref, fls, frs, disp0, out);
    }
}

// Round 6
// 162.478 us; speedup vs baseline: 2.2660x; 2.2660x over previous
//
#include <hip/hip_runtime.h>

// Cost volume: B=4, C=32, H=256, W=256, D=9, G=8, cpg=4
// out[b,g,d,h,w] = mean_{c in group g} var(warp_l, warp_r, feat_ref)
//
// R7: dwordx2 everywhere at HIGH occupancy. The request-granularity matrix:
//   4B/lane + high occ  = 55.5us (R1/R2/R3)
//   16B/lane + 9% occ   = 66us   (R5 - confounded by occupancy collapse)
//   16B/lane + high occ = 6.3 TB/s (the m13 copy ceiling itself)
// This fills the missing cell: 8B/lane with occupancy protected.
//  - 128-thread blocks (2 waves), one row of one (b,g), 2 px/thread.
//  - ALL global traffic is dwordx2: staging (8 loads), fref (4), disp (1),
//    output (9 stores). Request count halves at identical bytes.
//  - R3's verified LDS core + hat-weight/Q-S^2/3 math unchanged.
//  - Grid: g in high bits -> consecutive blocks stream consecutive rows of
//    the same 13 planes (DRAM page locality for reads and writes).

#define B_ 4
#define C_ 32
#define H_ 256
#define W_ 256
#define D_ 9
#define G_ 8
#define CPG 4
#define HW_ (H_ * W_)
#define SWPAD 264   // slots 0..259 used (x in [-2, W+1]); padded stride

typedef float v2f __attribute__((ext_vector_type(2)));

static __device__ __forceinline__ v2f sp(float x) { v2f r; r.x = x; r.y = x; return r; }

__global__ __launch_bounds__(128) void cost_volume_kernel(
    const float* __restrict__ fref,
    const float* __restrict__ fls,
    const float* __restrict__ frs,
    const float* __restrict__ disp0,
    float* __restrict__ out)
{
    const float kRes[D_] = {-0.4f, -0.3f, -0.2f, -0.1f, 0.0f,
                             0.1f,  0.2f,  0.3f,  0.4f};

    __shared__ float sL[CPG][SWPAD];
    __shared__ float sR[CPG][SWPAD];

    // g in HIGH bits: consecutive bids sweep h within one (b,g)
    const int bid = blockIdx.x;
    const int h = bid & (H_ - 1);
    const int b = (bid >> 8) & (B_ - 1);
    const int g = bid >> 10;
    const int t = threadIdx.x;          // 0..127
    const int w0 = t << 1;              // pixels w0, w0+1

    // disp for both pixels (dwordx2)
    const v2f dsp = *(const v2f*)(disp0 + (unsigned)((b * H_ + h) * W_ + w0));

    const unsigned rowbase = (unsigned)(((b * C_ + g * CPG) * HW_) + h * W_);
    const float* __restrict__ refrow = fref + rowbase;
    const float* __restrict__ lsrow  = fls  + rowbase;
    const float* __restrict__ rsrow  = frs  + rowbase;

    // ---- stage L/R rows (halo'd) into LDS, all dwordx2 ----
    {
        const int x0 = w0 - 2;                        // even, -2..252
        const bool v = (x0 >= 0);                     // only thread 0 is OOB
        #pragma unroll
        for (int cc = 0; cc < CPG; ++cc) {
            v2f mv = v ? *(const v2f*)(lsrow + cc * HW_ + x0) : sp(0.0f);
            *(v2f*)&sL[cc][w0] = mv;                  // slots x0+2 = w0, w0+1
            v2f mr = v ? *(const v2f*)(rsrow + cc * HW_ + x0) : sp(0.0f);
            *(v2f*)&sR[cc][w0] = mr;
        }
        if (t < 16) {                                 // halo slots 256..259
            const int side = t >> 3;                  // 0=L 1=R
            const int cc   = (t >> 1) & 3;
            const int part = t & 1;                   // 0: x=254,255  1: x=256,257
            v2f hv = sp(0.0f);
            if (part == 0) {
                const float* src = (side ? rsrow : lsrow) + cc * HW_ + 254;
                hv = *(const v2f*)src;
            }
            float* dst = side ? &sR[cc][256 + 2 * part] : &sL[cc][256 + 2 * part];
            *(v2f*)dst = hv;
        }
    }

    // fref for both pixels, all 4 channels (dwordx2)
    v2f F[CPG];
    #pragma unroll
    for (int cc = 0; cc < CPG; ++cc)
        F[cc] = *(const v2f*)(refrow + cc * HW_ + w0);

    __syncthreads();

    const unsigned obase = (unsigned)(((b * G_ + g) * D_) * HW_ + h * W_ + w0);
    float vals0[D_];                                  // pixel-0 stash

    #pragma unroll
    for (int p = 0; p < 2; ++p) {
        const int w = w0 + p;
        const float wf = (float)w;
        const float dbase = p ? dsp.y : dsp.x;

        // ---- disp-dependent setup (R3 math, verified) ----
        const float s0 = wf + dbase;
        const int i0l = (int)floorf(s0 - 0.4f);
        int relL = i0l - w;
        relL = relL < -1 ? -1 : (relL > 0 ? 0 : relL);
        const float a1l = (s0 - (float)(w + relL)) - 1.0f;

        const float s1 = wf - dbase;
        const int i0r = (int)floorf(s1 - 0.4f);
        int relR = i0r - w;
        relR = relR < -2 ? -2 : (relR > -1 ? -1 : relR);
        const float a1r = (s1 - (float)(w + relR)) - 1.0f;

        const int baseL = w + relL + 2;
        const int baseR = w + relR + 2;

        v2f fr01, fr23;
        fr01.x = p ? F[0].y : F[0].x;  fr01.y = p ? F[1].y : F[1].x;
        fr23.x = p ? F[2].y : F[2].x;  fr23.y = p ? F[3].y : F[3].x;
        const float frq = fr01.x * fr01.x + fr01.y * fr01.y
                        + fr23.x * fr23.x + fr23.y * fr23.y;

        v2f tl01[3], tl23[3], tr01[3], tr23[3];
        #pragma unroll
        for (int k = 0; k < 3; ++k) {
            tl01[k].x = sL[0][baseL + k];
            tl01[k].y = sL[1][baseL + k];
            tl23[k].x = sL[2][baseL + k];
            tl23[k].y = sL[3][baseL + k];
            tr01[k].x = sR[0][baseR + k];
            tr01[k].y = sR[1][baseR + k];
            tr23[k].x = sR[2][baseR + k];
            tr23[k].y = sR[3][baseR + k];
        }

        #pragma unroll
        for (int d = 0; d < D_; ++d) {
            const float tlw = a1l + kRes[d];
            const float W0l = fmaxf(-tlw, 0.0f);
            const float W1l = 1.0f - fabsf(tlw);
            const float W2l = fmaxf(tlw, 0.0f);
            const float trw = a1r - kRes[d];
            const float W0r = fmaxf(-trw, 0.0f);
            const float W1r = 1.0f - fabsf(trw);
            const float W2r = fmaxf(trw, 0.0f);

            v2f wl01 = tl01[0] * sp(W0l) + tl01[1] * sp(W1l) + tl01[2] * sp(W2l);
            v2f wl23 = tl23[0] * sp(W0l) + tl23[1] * sp(W1l) + tl23[2] * sp(W2l);
            v2f wr01 = tr01[0] * sp(W0r) + tr01[1] * sp(W1r) + tr01[2] * sp(W2r);
            v2f wr23 = tr23[0] * sp(W0r) + tr23[1] * sp(W1r) + tr23[2] * sp(W2r);

            v2f q   = wl01 * wl01 + wr01 * wr01 + wl23 * wl23 + wr23 * wr23;
            v2f s01 = wl01 + wr01 + fr01;
            v2f s23 = wl23 + wr23 + fr23;
            v2f s2  = s01 * s01 + s23 * s23;

            const float Q  = q.x + q.y + frq;
            const float S2 = s2.x + s2.y;
            const float val = (Q - S2 * (1.0f / 3.0f)) * (1.0f / 12.0f);

            if (p == 0) {
                vals0[d] = val;
            } else {
                v2f o; o.x = vals0[d]; o.y = val;     // dwordx2 store
                __builtin_nontemporal_store(
                    o, (v2f*)(out + obase + (unsigned)d * (unsigned)HW_));
            }
        }
    }
}

extern "C" void kernel_launch(void* const* d_in, const int* in_sizes, int n_in,
                              void* d_out, int out_size, void* d_ws, size_t ws_size,
                              hipStream_t stream) {
    const float* fref  = (const float*)d_in[0];
    const float* fls   = (const float*)d_in[1];
    const float* frs   = (const float*)d_in[2];
    const float* disp0 = (const float*)d_in[3];
    float* out = (float*)d_out;

    dim3 grid(B_ * G_ * H_);    // 8192 blocks; g in high bits
    dim3 block(128);
    cost_volume_kernel<<<grid, block, 0, stream>>>(fref, fls, frs, disp0, out);
}